// Round 10
// baseline (644.376 us; speedup 1.0000x reference)
//
#include <hip/hip_runtime.h>
#include <hip/hip_bf16.h>

#define Nn 50000
#define Ee 1600000
#define Ff 64
#define Rr 5
#define Bb 4
#define Ll 4
#define Kk 2048
#define NBK 196            // dst buckets (dst>>8)
#define SEGB 1280          // segs per bucket = 5 r * 256 dst
#define MsegP (NBK*SEGB)   // 250880 padded segs; s2 = b*1280 + r*256 + dstlo
#define NT32 1563          // 32-row tiles (ceil Nn/32)
#define NCH ((Ee+8191)/8192) // 196 edge chunks
#define WTSL (12*4*64*8)   // 24576 ushorts per layer (swizzled B-frags)

typedef __attribute__((ext_vector_type(8))) short short8;
typedef __attribute__((ext_vector_type(4))) float v4f;

// ---- bf16 pack/unpack helpers (storage bf16, math fp32) ----
static __device__ __forceinline__ unsigned short f2b(float f){
  unsigned u = __float_as_uint(f);
  unsigned r = (u + 0x7fffu + ((u>>16)&1u)) >> 16;   // RTN-even
  return (unsigned short)r;
}
static __device__ __forceinline__ unsigned packbf(float lo, float hi){
  return (unsigned)f2b(lo) | ((unsigned)f2b(hi) << 16);
}
static __device__ __forceinline__ float2 unpackbf(unsigned u){
  return make_float2(__uint_as_float(u << 16), __uint_as_float(u & 0xffff0000u));
}
static __device__ __forceinline__ void acc8(float* A, uint4 g){
  float2 f;
  f=unpackbf(g.x); A[0]+=f.x; A[1]+=f.y;
  f=unpackbf(g.y); A[2]+=f.x; A[3]+=f.y;
  f=unpackbf(g.z); A[4]+=f.x; A[5]+=f.y;
  f=unpackbf(g.w); A[6]+=f.x; A[7]+=f.y;
}

// ---- fused setup A: x2b | inv_init | w1eff | W-swizzle | t32f-zero | misc-zero ----
#define XB_B 6250
#define IV_B (XB_B+196)
#define WE_B (IV_B+128)
#define WS_B (WE_B+48)
#define TF_B (WS_B+7)
__global__ __launch_bounds__(256) void k_setupA(const float* __restrict__ x, unsigned* __restrict__ xb,
    int* __restrict__ inv, const float* __restrict__ w1, float* __restrict__ w1e,
    const float* __restrict__ bases, const float* __restrict__ comps, const float* __restrict__ roots,
    unsigned short* __restrict__ WTs, int* __restrict__ t32f, int* __restrict__ bcnt,
    int* __restrict__ bfill, unsigned* __restrict__ hA, unsigned* __restrict__ hB)
{
  int b = blockIdx.x, t = threadIdx.x;
  if (b < XB_B){
    int idx = b*256 + t;                      // < Nn*32 exactly
    int n = idx >> 5, j = idx & 31;
    float2 v = *(const float2*)&x[(size_t)n*64 + 2*j];
    xb[idx] = packbf(v.x, v.y);
  } else if (b < IV_B){
    int i = (b-XB_B)*256 + t;
    if (i < Nn) inv[i] = -1;
  } else if (b < WE_B){
    int idx = (b-IV_B)*256 + t;               // < 256*128 exactly
    int i = idx >> 7, j = idx & 127;
    w1e[idx] = w1[i*128 + j] + w1[(i+256)*128 + j];
  } else if (b < WS_B){
    int gid = (b-WE_B)*256 + t;               // < 12288 exactly
    int lane = gid & 63, nb = (gid>>6)&3, idx2 = gid>>8;  // idx2 = l*12+kk
    int l = idx2/12, kk = idx2 - l*12;
    int o = nb*16 + (lane & 15);
    int kbase = kk*32 + (lane>>4)*8;
    const float* basesl = bases + (size_t)l*Bb*Ff*Ff;
    const float* compsl = comps + (size_t)l*Rr*Bb;
    const float* rootsl = roots + (size_t)l*Ff*Ff;
    unsigned short* wp = WTs + (size_t)gid*8;
    #pragma unroll
    for (int j=0;j<8;j++){
      int k = kbase + j;
      float s;
      if (k < 320){
        int c = k >> 6, i = k & 63;
        s = 0.f;
        #pragma unroll
        for (int bb2=0;bb2<Bb;bb2++)
          s += compsl[c*Bb+bb2] * basesl[(bb2*Ff + i)*Ff + o];
      } else {
        s = rootsl[(k-320)*Ff + o];
      }
      wp[j] = f2b(s);
    }
  } else if (b < TF_B){
    int i = (b-WS_B)*256 + t;
    if (i < NT32) t32f[i] = 0;
  } else {
    if (t < NBK+1) bcnt[t] = 0;
    if (t < NBK) bfill[t] = 0;
    if (t < 32){
      xb[(size_t)Nn*32 + t] = 0;              // sentinel rows (zero)
      hA[(size_t)Nn*32 + t] = 0;
      hB[(size_t)Nn*32 + t] = 0;
    }
  }
}

// ---- setup B: target-index writes (blocks 0..7) + bucket histogram (blocks 8..8+NCH)
__global__ __launch_bounds__(256) void k_setupB(const int* __restrict__ tidx, int* __restrict__ inv,
                                                int* __restrict__ t32f, const int* __restrict__ ei,
                                                int* __restrict__ bcnt){
  int b = blockIdx.x;
  if (b < 8){
    int k = b*256 + threadIdx.x;
    if (k < Kk){
      int n = tidx[k];
      inv[n] = k;
      t32f[n >> 5] = 1;   // benign race; 32-row tiles
    }
  } else {
    __shared__ int h[NBK];
    int t = threadIdx.x;
    for (int i=t;i<NBK;i+=256) h[i]=0;
    __syncthreads();
    int base = (b-8)*8192;
    for (int i=0;i<32;i++){
      int e = base + i*256 + t;
      if (e < Ee) atomicAdd(&h[ei[Ee+e]>>8], 1);
    }
    __syncthreads();
    for (int i=t;i<NBK;i+=256) if (h[i]) atomicAdd(&bcnt[i], h[i]);
  }
}

// bin edges into bucket-grouped ebin[]; packed u32 = src | dstlo8<<16 | r<<24
// bucket bases computed locally from bcnt (196-entry LDS scan); bfill = global cursors (0-based)
__global__ __launch_bounds__(256) void k_bin(const int* __restrict__ ei, const int* __restrict__ et,
                                             const int* __restrict__ bcnt, int* __restrict__ bfill,
                                             unsigned* __restrict__ ebin){
  __shared__ unsigned led[8192];
  __shared__ int h[NBK], gb[NBK];
  __shared__ int ex[256];
  int t = threadIdx.x;
  for (int i=t;i<NBK;i+=256) h[i]=0;
  int v = (t < NBK) ? bcnt[t] : 0;
  ex[t] = v;
  __syncthreads();
  int base = blockIdx.x*8192;
  for (int i=0;i<32;i++){
    int e = base + i*256 + t;
    if (e < Ee){
      int src = ei[e];
      int dst = ei[Ee+e];
      int r = et[e];
      led[i*256+t] = (unsigned)src | ((unsigned)(dst&255)<<16) | ((unsigned)r<<24);
      atomicAdd(&h[dst>>8], 1);
    }
  }
  __syncthreads();
  #pragma unroll
  for (int off=1; off<256; off<<=1){
    int x = (t>=off) ? ex[t-off] : 0;
    __syncthreads();
    ex[t] += x;
    __syncthreads();
  }
  if (t < NBK && h[t]){ gb[t] = ex[t] - v + atomicAdd(&bfill[t], h[t]); }
  if (t < NBK) h[t] = 0;
  __syncthreads();
  for (int i=0;i<32;i++){
    int e = base + i*256 + t;
    if (e < Ee){
      int b2 = ei[Ee+e]>>8;
      int off = atomicAdd(&h[b2], 1);
      ebin[gb[b2]+off] = led[i*256+t];
    }
  }
}

// per-bucket seg sort: counts -> scan -> rowptr + scatter srcs (bucket-private region)
// bucket base computed locally by reducing bcnt[0..b)
__global__ __launch_bounds__(512) void k_sort(const unsigned* __restrict__ ebin, const int* __restrict__ bcnt,
                                              unsigned short* __restrict__ srcs, int* __restrict__ rowptr){
  __shared__ int cntA[SEGB], excA[SEGB];
  __shared__ int red[512];
  int b = blockIdx.x, t = threadIdx.x;
  red[t] = (t < b) ? bcnt[t] : 0;
  __syncthreads();
  #pragma unroll
  for (int off=256; off>0; off>>=1){
    if (t < off) red[t] += red[t+off];
    __syncthreads();
  }
  int base = red[0];
  int cnt = bcnt[b];
  if (b == 0 && t == 0) rowptr[MsegP] = Ee;
  for (int i=t;i<SEGB;i+=512) cntA[i]=0;
  __syncthreads();
  for (int i=t;i<cnt;i+=512){
    unsigned u = ebin[base+i];
    int segl = (int)((u>>24)&7u)*256 + (int)((u>>16)&255u);
    atomicAdd(&cntA[segl], 1);
  }
  __syncthreads();
  for (int i=t;i<SEGB;i+=512) excA[i]=cntA[i];
  __syncthreads();
  for (int off=1; off<SEGB; off<<=1){
    int i0=t, i1=t+512, i2=t+1024;
    int v0 = (i0>=off)? excA[i0-off] : 0;
    int v1 = (i1>=off)? excA[i1-off] : 0;
    int v2 = (i2<SEGB && i2>=off)? excA[i2-off] : 0;
    __syncthreads();
    excA[i0]+=v0;
    excA[i1]+=v1;
    if (i2<SEGB) excA[i2]+=v2;
    __syncthreads();
  }
  for (int i=t;i<SEGB;i+=512){
    int ex = excA[i]-cntA[i];
    excA[i] = ex;
    rowptr[b*SEGB+i] = base + ex;
    cntA[i] = 0;
  }
  __syncthreads();
  for (int i=t;i<cnt;i+=512){
    unsigned u = ebin[base+i];
    int segl = (int)((u>>24)&7u)*256 + (int)((u>>16)&255u);
    int off = atomicAdd(&cntA[segl], 1);
    srcs[base + excA[segl] + off] = (unsigned short)(u & 0xffffu);
  }
}

#define LDROW(IDX) (*(const uint4*)&h2[(size_t)(IDX)*32 + li*4])

// ---- fused aggregation + MFMA combine (R8 structure, 8 blocks/CU).
// Phase 1: 32 groups of 8 lanes; group g owns segment (r, dst=d0+g).
//          Metadata prefetched; 12 flat sentinel-padded slots (P(deg>12)=1.7%),
//          8-deep load pipeline, no gating. Divergent tail for deg>12 reloads
//          its rowptr entry (keeps p[] short-lived -> VGPR<=64 for 8 blocks/CU).
// Phase 2: 4 waves do [32,384]@[384,64] MFMA (2 row-blocks per wave).
// __launch_bounds__(256,8): 8 waves/SIMD; 8 x 20 KB LDS = 160 KB = full CU LDS.
// Layer Ll-1 is gated by t32f (tiles containing a target node) and skips hn.
__global__ __launch_bounds__(256, 8) void k_fused(const unsigned short* __restrict__ srcs,
    const int* __restrict__ rowptr, const unsigned* __restrict__ h2,
    const unsigned short* __restrict__ WTsl, const float* __restrict__ bias,
    unsigned short* __restrict__ hn, const int* __restrict__ inv, float* __restrict__ sel,
    int layer, const int* __restrict__ t32f)
{
  if (layer == Ll-1 && t32f[blockIdx.x] == 0) return;
  __shared__ __align__(16) unsigned short ytile[5*32*64];   // 20 KB, XOR-swizzled rows
  char* yb = (char*)ytile;
  int tid = threadIdx.x;
  int grp = tid >> 3;                 // 0..31: dst row within tile
  int li  = tid & 7;                  // 16 B slice of the 128 B feature row
  int grp8 = (tid & 63) & 56;         // group base lane within the wave
  int d0 = blockIdx.x * 32;
  int segbase = (d0 >> 8)*SEGB + (d0 & 255) + grp;

  // prefetch all per-r metadata: 10 independent rowptr loads, then srcs bursts
  int p[Rr], dg[Rr];
  #pragma unroll
  for (int r=0;r<Rr;r++){
    p[r]  = rowptr[segbase + r*256];
    dg[r] = rowptr[segbase + r*256 + 1] - p[r];
  }
  unsigned b0[Rr], b1r[Rr];
  #pragma unroll
  for (int r=0;r<Rr;r++){
    b0[r]  = srcs[p[r] + li];          // srcs padded by 64
    b1r[r] = srcs[p[r] + 8 + li];
  }

  #pragma unroll
  for (int r=0;r<Rr;r++){
    int deg = dg[r];
    int id[12];
    #pragma unroll
    for (int j=0;j<12;j++){
      int vsh = __shfl((int)((j<8)? b0[r] : b1r[r]), grp8 + (j&7), 64);
      id[j] = (j < deg) ? vsh : Nn;     // sentinel row = zeros (L1-hot)
    }
    float A[8] = {0.f,0.f,0.f,0.f,0.f,0.f,0.f,0.f};
    uint4 g0=LDROW(id[0]), g1=LDROW(id[1]), g2=LDROW(id[2]), g3=LDROW(id[3]),
          g4=LDROW(id[4]), g5=LDROW(id[5]), g6=LDROW(id[6]), g7=LDROW(id[7]);
    acc8(A,g0); g0=LDROW(id[ 8]);
    acc8(A,g1); g1=LDROW(id[ 9]);
    acc8(A,g2); g2=LDROW(id[10]);
    acc8(A,g3); g3=LDROW(id[11]);
    acc8(A,g4); acc8(A,g5); acc8(A,g6); acc8(A,g7);
    acc8(A,g0); acc8(A,g1); acc8(A,g2); acc8(A,g3);
    if (deg > 12){                       // rare (1.7%): reload base, divergent tail
      int pb = rowptr[segbase + r*256];
      for (int j=12;j<deg;j++){
        uint4 gt = LDROW((int)srcs[pb+j]);
        acc8(A, gt);
      }
    }
    float sc = (deg > 0) ? 1.0f/(float)deg : 0.f;
    uint4 o;
    o.x = packbf(A[0]*sc, A[1]*sc);
    o.y = packbf(A[2]*sc, A[3]*sc);
    o.z = packbf(A[4]*sc, A[5]*sc);
    o.w = packbf(A[6]*sc, A[7]*sc);
    int tr = r*32 + grp;
    *(uint4*)(yb + ((tr*128 + li*16) ^ ((tr&7)<<4))) = o;
  }
  __syncthreads();

  // ---- MFMA phase: wave wv owns output columns [wv*16, wv*16+16), 2 row-blocks
  int wv = tid >> 6;
  int lane = tid & 63;
  int m = lane & 15, q = lane >> 4;
  const unsigned short* wp = WTsl + (size_t)lane*8 + (size_t)wv*512;
  const char* h2c = (const char*)h2;
  int row0 = d0 + m, row1 = d0 + 16 + m;
  int row0c = (row0 < Nn) ? row0 : Nn-1;
  int row1c = (row1 < Nn) ? row1 : Nn-1;
  v4f acc0 = {0.f,0.f,0.f,0.f}, acc1 = {0.f,0.f,0.f,0.f};
  #pragma unroll
  for (int kk=0; kk<12; kk++){
    short8 a0, a1;
    if (kk < 10){
      int rb = (kk>>1)*32;
      a0 = *(const short8*)(yb + (((rb+m   )*128 + (kk&1)*64 + q*16) ^ ((m&7)<<4)));
      a1 = *(const short8*)(yb + (((rb+16+m)*128 + (kk&1)*64 + q*16) ^ ((m&7)<<4)));
    } else {
      a0 = *(const short8*)(h2c + (size_t)row0c*128 + (size_t)(kk&1)*64 + q*16);
      a1 = *(const short8*)(h2c + (size_t)row1c*128 + (size_t)(kk&1)*64 + q*16);
    }
    short8 bf = *(const short8*)(wp + (size_t)kk*2048);
    acc0 = __builtin_amdgcn_mfma_f32_16x16x32_bf16(a0, bf, acc0, 0, 0, 0);
    acc1 = __builtin_amdgcn_mfma_f32_16x16x32_bf16(a1, bf, acc1, 0, 0, 0);
  }
  float bc = bias[wv*16 + m];
  #pragma unroll
  for (int j=0;j<4;j++){
    int node0 = d0 + q*4 + j;
    int node1 = d0 + 16 + q*4 + j;
    float r0 = tanhf(acc0[j] + bc);
    float r1 = tanhf(acc1[j] + bc);
    if (node0 < Nn){
      if (layer != Ll-1) hn[(size_t)node0*64 + wv*16 + m] = f2b(r0);
      int k = inv[node0];
      if (k >= 0) sel[(size_t)k*256 + layer*64 + wv*16 + m] = r0;
    }
    if (node1 < Nn){
      if (layer != Ll-1) hn[(size_t)node1*64 + wv*16 + m] = f2b(r1);
      int k = inv[node1];
      if (k >= 0) sel[(size_t)k*256 + layer*64 + wv*16 + m] = r1;
    }
  }
}

__global__ __launch_bounds__(128) void k_mlp(const float* __restrict__ sel, const float* __restrict__ w1e,
    const float* __restrict__ b1, const float* __restrict__ w2, const float* __restrict__ b2,
    float* __restrict__ out)
{
  __shared__ float sfeat[256];
  __shared__ float partial[2];
  int k = blockIdx.x, j = threadIdx.x;
  for (int idx=j; idx<256; idx+=128) sfeat[idx] = sel[(size_t)k*256 + idx];
  __syncthreads();
  float a = b1[j];
  for (int i=0;i<256;i++) a += sfeat[i] * w1e[i*128 + j];
  a = fmaxf(a, 0.f);
  float v = a * w2[j];
  #pragma unroll
  for (int off=32; off>0; off>>=1) v += __shfl_down(v, off, 64);
  if ((j & 63) == 0) partial[j>>6] = v;
  __syncthreads();
  if (j == 0) out[k] = partial[0] + partial[1] + b2[0];
}

extern "C" void kernel_launch(void* const* d_in, const int* in_sizes, int n_in,
                              void* d_out, int out_size, void* d_ws, size_t ws_size,
                              hipStream_t stream){
  const float* x     = (const float*)d_in[0];
  const int*  ei     = (const int*)d_in[1];
  const int*  et     = (const int*)d_in[2];
  const int*  tidx   = (const int*)d_in[3];
  const float* bases = (const float*)d_in[4];
  const float* comps = (const float*)d_in[5];
  const float* roots = (const float*)d_in[6];
  const float* biases= (const float*)d_in[7];
  const float* w1    = (const float*)d_in[8];
  const float* b1    = (const float*)d_in[9];
  const float* w2    = (const float*)d_in[10];
  const float* b2    = (const float*)d_in[11];
  float* out = (float*)d_out;

  char* wsp = (char*)d_ws;
  size_t off = 0;
  auto alloc = [&](size_t bytes)->void*{ void* p = wsp + off; off += (bytes + 255) & ~size_t(255); return p; };
  unsigned* xb    = (unsigned*)alloc(sizeof(unsigned)*((size_t)Nn+1)*32);  // +sentinel row
  unsigned* hA    = (unsigned*)alloc(sizeof(unsigned)*((size_t)Nn+1)*32);
  unsigned* hB    = (unsigned*)alloc(sizeof(unsigned)*((size_t)Nn+1)*32);
  unsigned* ebin  = (unsigned*)alloc(sizeof(unsigned)*(size_t)Ee);         // 6.4 MB
  int*      bcnt  = (int*)  alloc(sizeof(int)*(NBK+1));
  int*      bfill = (int*)  alloc(sizeof(int)*(NBK));
  int*      rowptr= (int*)  alloc(sizeof(int)*(MsegP+1));                  // 1 MB
  unsigned short* srcs = (unsigned short*)alloc(sizeof(unsigned short)*((size_t)Ee+64)); // padded
  unsigned short* WTs  = (unsigned short*)alloc(sizeof(unsigned short)*(size_t)Ll*WTSL);
  float*    sel   = (float*)alloc(sizeof(float)*(size_t)Kk*256);           // 2 MB
  float*    w1e   = (float*)alloc(sizeof(float)*256*128);
  int*      inv   = (int*)  alloc(sizeof(int)*(size_t)Nn);
  int*      t32f  = (int*)  alloc(sizeof(int)*NT32);
  (void)ws_size;

  k_setupA<<<TF_B+1, 256, 0, stream>>>(x, xb, inv, w1, w1e, bases, comps, roots,
                                       WTs, t32f, bcnt, bfill, hA, hB);
  k_setupB<<<8+NCH, 256, 0, stream>>>(tidx, inv, t32f, ei, bcnt);
  k_bin<<<NCH, 256, 0, stream>>>(ei, et, bcnt, bfill, ebin);
  k_sort<<<NBK, 512, 0, stream>>>(ebin, bcnt, srcs, rowptr);

  const unsigned* hc = xb;
  unsigned* hn = hA;
  for (int l=0;l<Ll;l++){
    k_fused<<<NT32, 256, 0, stream>>>(srcs, rowptr, hc, WTs + (size_t)l*WTSL,
                                      biases + (size_t)l*Ff, (unsigned short*)hn,
                                      inv, sel, l, t32f);
    hc = hn;
    hn = (hn == hA) ? hB : hA;
  }
  k_mlp<<<Kk, 128, 0, stream>>>(sel, w1e, b1, w2, b2, out);
}

// Round 11
// 282.566 us; speedup vs baseline: 2.2804x; 2.2804x over previous
//
#include <hip/hip_runtime.h>
#include <hip/hip_bf16.h>

#define Nn 50000
#define Ee 1600000
#define Ff 64
#define Rr 5
#define Bb 4
#define Ll 4
#define Kk 2048
#define NBK 196            // dst buckets (dst>>8)
#define SEGB 1280          // segs per bucket = 5 r * 256 dst
#define MsegP (NBK*SEGB)   // 250880 padded segs; s2 = b*1280 + r*256 + dstlo
#define NT32 1563          // 32-row tiles (ceil Nn/32)
#define NCH ((Ee+8191)/8192) // 196 edge chunks
#define WTSL (12*4*64*8)   // 24576 ushorts per layer (swizzled B-frags)

typedef __attribute__((ext_vector_type(8))) short short8;
typedef __attribute__((ext_vector_type(4))) float v4f;
typedef __attribute__((ext_vector_type(2))) float f32x2;

// ---- bf16 pack/unpack helpers (storage bf16, math fp32) ----
static __device__ __forceinline__ unsigned short f2b(float f){
  unsigned u = __float_as_uint(f);
  unsigned r = (u + 0x7fffu + ((u>>16)&1u)) >> 16;   // RTN-even
  return (unsigned short)r;
}
static __device__ __forceinline__ unsigned packbf(float lo, float hi){
  return (unsigned)f2b(lo) | ((unsigned)f2b(hi) << 16);
}
static __device__ __forceinline__ float2 unpackbf(unsigned u){
  return make_float2(__uint_as_float(u << 16), __uint_as_float(u & 0xffff0000u));
}
// packed accumulate: per-component add chains identical to scalar version
// (bit-identical result); clang lowers <2 x float> fadd to v_pk_add_f32.
static __device__ __forceinline__ void acc8(f32x2* A, uint4 g){
  A[0] += (f32x2){__uint_as_float(g.x << 16), __uint_as_float(g.x & 0xffff0000u)};
  A[1] += (f32x2){__uint_as_float(g.y << 16), __uint_as_float(g.y & 0xffff0000u)};
  A[2] += (f32x2){__uint_as_float(g.z << 16), __uint_as_float(g.z & 0xffff0000u)};
  A[3] += (f32x2){__uint_as_float(g.w << 16), __uint_as_float(g.w & 0xffff0000u)};
}

// ---- fused setup A: x2b | inv_init | w1eff | W-swizzle | t32f-zero | misc-zero ----
#define XB_B 6250
#define IV_B (XB_B+196)
#define WE_B (IV_B+128)
#define WS_B (WE_B+48)
#define TF_B (WS_B+7)
__global__ __launch_bounds__(256) void k_setupA(const float* __restrict__ x, unsigned* __restrict__ xb,
    int* __restrict__ inv, const float* __restrict__ w1, float* __restrict__ w1e,
    const float* __restrict__ bases, const float* __restrict__ comps, const float* __restrict__ roots,
    unsigned short* __restrict__ WTs, int* __restrict__ t32f, int* __restrict__ bcnt,
    int* __restrict__ bfill, unsigned* __restrict__ hA, unsigned* __restrict__ hB)
{
  int b = blockIdx.x, t = threadIdx.x;
  if (b < XB_B){
    int idx = b*256 + t;                      // < Nn*32 exactly
    int n = idx >> 5, j = idx & 31;
    float2 v = *(const float2*)&x[(size_t)n*64 + 2*j];
    xb[idx] = packbf(v.x, v.y);
  } else if (b < IV_B){
    int i = (b-XB_B)*256 + t;
    if (i < Nn) inv[i] = -1;
  } else if (b < WE_B){
    int idx = (b-IV_B)*256 + t;               // < 256*128 exactly
    int i = idx >> 7, j = idx & 127;
    w1e[idx] = w1[i*128 + j] + w1[(i+256)*128 + j];
  } else if (b < WS_B){
    int gid = (b-WE_B)*256 + t;               // < 12288 exactly
    int lane = gid & 63, nb = (gid>>6)&3, idx2 = gid>>8;  // idx2 = l*12+kk
    int l = idx2/12, kk = idx2 - l*12;
    int o = nb*16 + (lane & 15);
    int kbase = kk*32 + (lane>>4)*8;
    const float* basesl = bases + (size_t)l*Bb*Ff*Ff;
    const float* compsl = comps + (size_t)l*Rr*Bb;
    const float* rootsl = roots + (size_t)l*Ff*Ff;
    unsigned short* wp = WTs + (size_t)gid*8;
    #pragma unroll
    for (int j=0;j<8;j++){
      int k = kbase + j;
      float s;
      if (k < 320){
        int c = k >> 6, i = k & 63;
        s = 0.f;
        #pragma unroll
        for (int bb2=0;bb2<Bb;bb2++)
          s += compsl[c*Bb+bb2] * basesl[(bb2*Ff + i)*Ff + o];
      } else {
        s = rootsl[(k-320)*Ff + o];
      }
      wp[j] = f2b(s);
    }
  } else if (b < TF_B){
    int i = (b-WS_B)*256 + t;
    if (i < NT32) t32f[i] = 0;
  } else {
    if (t < NBK+1) bcnt[t] = 0;
    if (t < NBK) bfill[t] = 0;
    if (t < 32){
      xb[(size_t)Nn*32 + t] = 0;              // sentinel rows (zero)
      hA[(size_t)Nn*32 + t] = 0;
      hB[(size_t)Nn*32 + t] = 0;
    }
  }
}

// ---- setup B: target-index writes (blocks 0..7) + bucket histogram (blocks 8..8+NCH)
__global__ __launch_bounds__(256) void k_setupB(const int* __restrict__ tidx, int* __restrict__ inv,
                                                int* __restrict__ t32f, const int* __restrict__ ei,
                                                int* __restrict__ bcnt){
  int b = blockIdx.x;
  if (b < 8){
    int k = b*256 + threadIdx.x;
    if (k < Kk){
      int n = tidx[k];
      inv[n] = k;
      t32f[n >> 5] = 1;   // benign race; 32-row tiles
    }
  } else {
    __shared__ int h[NBK];
    int t = threadIdx.x;
    for (int i=t;i<NBK;i+=256) h[i]=0;
    __syncthreads();
    int base = (b-8)*8192;
    for (int i=0;i<32;i++){
      int e = base + i*256 + t;
      if (e < Ee) atomicAdd(&h[ei[Ee+e]>>8], 1);
    }
    __syncthreads();
    for (int i=t;i<NBK;i+=256) if (h[i]) atomicAdd(&bcnt[i], h[i]);
  }
}

// bin edges into bucket-grouped ebin[]; packed u32 = src | dstlo8<<16 | r<<24
// bucket bases computed locally from bcnt (196-entry LDS scan); bfill = global cursors (0-based)
__global__ __launch_bounds__(256) void k_bin(const int* __restrict__ ei, const int* __restrict__ et,
                                             const int* __restrict__ bcnt, int* __restrict__ bfill,
                                             unsigned* __restrict__ ebin){
  __shared__ unsigned led[8192];
  __shared__ int h[NBK], gb[NBK];
  __shared__ int ex[256];
  int t = threadIdx.x;
  for (int i=t;i<NBK;i+=256) h[i]=0;
  int v = (t < NBK) ? bcnt[t] : 0;
  ex[t] = v;
  __syncthreads();
  int base = blockIdx.x*8192;
  for (int i=0;i<32;i++){
    int e = base + i*256 + t;
    if (e < Ee){
      int src = ei[e];
      int dst = ei[Ee+e];
      int r = et[e];
      led[i*256+t] = (unsigned)src | ((unsigned)(dst&255)<<16) | ((unsigned)r<<24);
      atomicAdd(&h[dst>>8], 1);
    }
  }
  __syncthreads();
  #pragma unroll
  for (int off=1; off<256; off<<=1){
    int x = (t>=off) ? ex[t-off] : 0;
    __syncthreads();
    ex[t] += x;
    __syncthreads();
  }
  if (t < NBK && h[t]){ gb[t] = ex[t] - v + atomicAdd(&bfill[t], h[t]); }
  if (t < NBK) h[t] = 0;
  __syncthreads();
  for (int i=0;i<32;i++){
    int e = base + i*256 + t;
    if (e < Ee){
      int b2 = ei[Ee+e]>>8;
      int off = atomicAdd(&h[b2], 1);
      ebin[gb[b2]+off] = led[i*256+t];
    }
  }
}

// per-bucket seg sort: counts -> scan -> rowptr + scatter srcs (bucket-private region)
// bucket base computed locally by reducing bcnt[0..b)
__global__ __launch_bounds__(512) void k_sort(const unsigned* __restrict__ ebin, const int* __restrict__ bcnt,
                                              unsigned short* __restrict__ srcs, int* __restrict__ rowptr){
  __shared__ int cntA[SEGB], excA[SEGB];
  __shared__ int red[512];
  int b = blockIdx.x, t = threadIdx.x;
  red[t] = (t < b) ? bcnt[t] : 0;
  __syncthreads();
  #pragma unroll
  for (int off=256; off>0; off>>=1){
    if (t < off) red[t] += red[t+off];
    __syncthreads();
  }
  int base = red[0];
  int cnt = bcnt[b];
  if (b == 0 && t == 0) rowptr[MsegP] = Ee;
  for (int i=t;i<SEGB;i+=512) cntA[i]=0;
  __syncthreads();
  for (int i=t;i<cnt;i+=512){
    unsigned u = ebin[base+i];
    int segl = (int)((u>>24)&7u)*256 + (int)((u>>16)&255u);
    atomicAdd(&cntA[segl], 1);
  }
  __syncthreads();
  for (int i=t;i<SEGB;i+=512) excA[i]=cntA[i];
  __syncthreads();
  for (int off=1; off<SEGB; off<<=1){
    int i0=t, i1=t+512, i2=t+1024;
    int v0 = (i0>=off)? excA[i0-off] : 0;
    int v1 = (i1>=off)? excA[i1-off] : 0;
    int v2 = (i2<SEGB && i2>=off)? excA[i2-off] : 0;
    __syncthreads();
    excA[i0]+=v0;
    excA[i1]+=v1;
    if (i2<SEGB) excA[i2]+=v2;
    __syncthreads();
  }
  for (int i=t;i<SEGB;i+=512){
    int ex = excA[i]-cntA[i];
    excA[i] = ex;
    rowptr[b*SEGB+i] = base + ex;
    cntA[i] = 0;
  }
  __syncthreads();
  for (int i=t;i<cnt;i+=512){
    unsigned u = ebin[base+i];
    int segl = (int)((u>>24)&7u)*256 + (int)((u>>16)&255u);
    int off = atomicAdd(&cntA[segl], 1);
    srcs[base + excA[segl] + off] = (unsigned short)(u & 0xffffu);
  }
}

#define LDROW(IDX) (*(const uint4*)&h2[(size_t)(IDX)*32 + li*4])

// ---- fused aggregation + MFMA combine (R8 structure, 4 blocks/CU).
// NOTE: __launch_bounds__(256,8) tried in R10 -> compiler targets 32 VGPR,
// spills gather pipeline to scratch (FETCH 53->270 MB), 2.3x regression.
// (256,4) binary is 64 VGPR / 20 KB LDS; HW can co-schedule 8 blocks anyway.
// Phase 1: 32 groups of 8 lanes; group g owns segment (r, dst=d0+g).
//          Metadata prefetched; 12 flat sentinel-padded slots (P(deg>12)=1.7%),
//          8-deep load pipeline, packed-f32 accumulate. Divergent tail deg>12.
// Phase 2: 4 waves do [32,384]@[384,64] MFMA (2 row-blocks per wave).
// Layer Ll-1 is gated by t32f (tiles containing a target node) and skips hn.
__global__ __launch_bounds__(256, 4) void k_fused(const unsigned short* __restrict__ srcs,
    const int* __restrict__ rowptr, const unsigned* __restrict__ h2,
    const unsigned short* __restrict__ WTsl, const float* __restrict__ bias,
    unsigned short* __restrict__ hn, const int* __restrict__ inv, float* __restrict__ sel,
    int layer, const int* __restrict__ t32f)
{
  if (layer == Ll-1 && t32f[blockIdx.x] == 0) return;
  __shared__ __align__(16) unsigned short ytile[5*32*64];   // 20 KB, XOR-swizzled rows
  char* yb = (char*)ytile;
  int tid = threadIdx.x;
  int grp = tid >> 3;                 // 0..31: dst row within tile
  int li  = tid & 7;                  // 16 B slice of the 128 B feature row
  int grp8 = (tid & 63) & 56;         // group base lane within the wave
  int d0 = blockIdx.x * 32;
  int segbase = (d0 >> 8)*SEGB + (d0 & 255) + grp;

  // prefetch all per-r metadata: 10 independent rowptr loads, then srcs bursts
  int p[Rr], dg[Rr];
  #pragma unroll
  for (int r=0;r<Rr;r++){
    p[r]  = rowptr[segbase + r*256];
    dg[r] = rowptr[segbase + r*256 + 1] - p[r];
  }
  unsigned b0[Rr], b1r[Rr];
  #pragma unroll
  for (int r=0;r<Rr;r++){
    b0[r]  = srcs[p[r] + li];          // srcs padded by 64
    b1r[r] = srcs[p[r] + 8 + li];
  }

  #pragma unroll
  for (int r=0;r<Rr;r++){
    int deg = dg[r];
    int id[12];
    #pragma unroll
    for (int j=0;j<12;j++){
      int vsh = __shfl((int)((j<8)? b0[r] : b1r[r]), grp8 + (j&7), 64);
      id[j] = (j < deg) ? vsh : Nn;     // sentinel row = zeros (L1-hot)
    }
    f32x2 A[4] = {{0.f,0.f},{0.f,0.f},{0.f,0.f},{0.f,0.f}};
    uint4 g0=LDROW(id[0]), g1=LDROW(id[1]), g2=LDROW(id[2]), g3=LDROW(id[3]),
          g4=LDROW(id[4]), g5=LDROW(id[5]), g6=LDROW(id[6]), g7=LDROW(id[7]);
    acc8(A,g0); g0=LDROW(id[ 8]);
    acc8(A,g1); g1=LDROW(id[ 9]);
    acc8(A,g2); g2=LDROW(id[10]);
    acc8(A,g3); g3=LDROW(id[11]);
    acc8(A,g4); acc8(A,g5); acc8(A,g6); acc8(A,g7);
    acc8(A,g0); acc8(A,g1); acc8(A,g2); acc8(A,g3);
    if (deg > 12){                       // rare (1.7% of segments): divergent tail
      for (int j=12;j<deg;j++){
        uint4 gt = LDROW((int)srcs[p[r]+j]);
        acc8(A, gt);
      }
    }
    float sc = (deg > 0) ? 1.0f/(float)deg : 0.f;
    uint4 o;
    o.x = packbf(A[0].x*sc, A[0].y*sc);
    o.y = packbf(A[1].x*sc, A[1].y*sc);
    o.z = packbf(A[2].x*sc, A[2].y*sc);
    o.w = packbf(A[3].x*sc, A[3].y*sc);
    int tr = r*32 + grp;
    *(uint4*)(yb + ((tr*128 + li*16) ^ ((tr&7)<<4))) = o;
  }
  __syncthreads();

  // ---- MFMA phase: wave wv owns output columns [wv*16, wv*16+16), 2 row-blocks
  int wv = tid >> 6;
  int lane = tid & 63;
  int m = lane & 15, q = lane >> 4;
  const unsigned short* wp = WTsl + (size_t)lane*8 + (size_t)wv*512;
  const char* h2c = (const char*)h2;
  int row0 = d0 + m, row1 = d0 + 16 + m;
  int row0c = (row0 < Nn) ? row0 : Nn-1;
  int row1c = (row1 < Nn) ? row1 : Nn-1;
  v4f acc0 = {0.f,0.f,0.f,0.f}, acc1 = {0.f,0.f,0.f,0.f};
  #pragma unroll
  for (int kk=0; kk<12; kk++){
    short8 a0, a1;
    if (kk < 10){
      int rb = (kk>>1)*32;
      a0 = *(const short8*)(yb + (((rb+m   )*128 + (kk&1)*64 + q*16) ^ ((m&7)<<4)));
      a1 = *(const short8*)(yb + (((rb+16+m)*128 + (kk&1)*64 + q*16) ^ ((m&7)<<4)));
    } else {
      a0 = *(const short8*)(h2c + (size_t)row0c*128 + (size_t)(kk&1)*64 + q*16);
      a1 = *(const short8*)(h2c + (size_t)row1c*128 + (size_t)(kk&1)*64 + q*16);
    }
    short8 bf = *(const short8*)(wp + (size_t)kk*2048);
    acc0 = __builtin_amdgcn_mfma_f32_16x16x32_bf16(a0, bf, acc0, 0, 0, 0);
    acc1 = __builtin_amdgcn_mfma_f32_16x16x32_bf16(a1, bf, acc1, 0, 0, 0);
  }
  float bc = bias[wv*16 + m];
  #pragma unroll
  for (int j=0;j<4;j++){
    int node0 = d0 + q*4 + j;
    int node1 = d0 + 16 + q*4 + j;
    float r0 = tanhf(acc0[j] + bc);
    float r1 = tanhf(acc1[j] + bc);
    if (node0 < Nn){
      if (layer != Ll-1) hn[(size_t)node0*64 + wv*16 + m] = f2b(r0);
      int k = inv[node0];
      if (k >= 0) sel[(size_t)k*256 + layer*64 + wv*16 + m] = r0;
    }
    if (node1 < Nn){
      if (layer != Ll-1) hn[(size_t)node1*64 + wv*16 + m] = f2b(r1);
      int k = inv[node1];
      if (k >= 0) sel[(size_t)k*256 + layer*64 + wv*16 + m] = r1;
    }
  }
}

__global__ __launch_bounds__(128) void k_mlp(const float* __restrict__ sel, const float* __restrict__ w1e,
    const float* __restrict__ b1, const float* __restrict__ w2, const float* __restrict__ b2,
    float* __restrict__ out)
{
  __shared__ float sfeat[256];
  __shared__ float partial[2];
  int k = blockIdx.x, j = threadIdx.x;
  for (int idx=j; idx<256; idx+=128) sfeat[idx] = sel[(size_t)k*256 + idx];
  __syncthreads();
  float a = b1[j];
  for (int i=0;i<256;i++) a += sfeat[i] * w1e[i*128 + j];
  a = fmaxf(a, 0.f);
  float v = a * w2[j];
  #pragma unroll
  for (int off=32; off>0; off>>=1) v += __shfl_down(v, off, 64);
  if ((j & 63) == 0) partial[j>>6] = v;
  __syncthreads();
  if (j == 0) out[k] = partial[0] + partial[1] + b2[0];
}

extern "C" void kernel_launch(void* const* d_in, const int* in_sizes, int n_in,
                              void* d_out, int out_size, void* d_ws, size_t ws_size,
                              hipStream_t stream){
  const float* x     = (const float*)d_in[0];
  const int*  ei     = (const int*)d_in[1];
  const int*  et     = (const int*)d_in[2];
  const int*  tidx   = (const int*)d_in[3];
  const float* bases = (const float*)d_in[4];
  const float* comps = (const float*)d_in[5];
  const float* roots = (const float*)d_in[6];
  const float* biases= (const float*)d_in[7];
  const float* w1    = (const float*)d_in[8];
  const float* b1    = (const float*)d_in[9];
  const float* w2    = (const float*)d_in[10];
  const float* b2    = (const float*)d_in[11];
  float* out = (float*)d_out;

  char* wsp = (char*)d_ws;
  size_t off = 0;
  auto alloc = [&](size_t bytes)->void*{ void* p = wsp + off; off += (bytes + 255) & ~size_t(255); return p; };
  unsigned* xb    = (unsigned*)alloc(sizeof(unsigned)*((size_t)Nn+1)*32);  // +sentinel row
  unsigned* hA    = (unsigned*)alloc(sizeof(unsigned)*((size_t)Nn+1)*32);
  unsigned* hB    = (unsigned*)alloc(sizeof(unsigned)*((size_t)Nn+1)*32);
  unsigned* ebin  = (unsigned*)alloc(sizeof(unsigned)*(size_t)Ee);         // 6.4 MB
  int*      bcnt  = (int*)  alloc(sizeof(int)*(NBK+1));
  int*      bfill = (int*)  alloc(sizeof(int)*(NBK));
  int*      rowptr= (int*)  alloc(sizeof(int)*(MsegP+1));                  // 1 MB
  unsigned short* srcs = (unsigned short*)alloc(sizeof(unsigned short)*((size_t)Ee+64)); // padded
  unsigned short* WTs  = (unsigned short*)alloc(sizeof(unsigned short)*(size_t)Ll*WTSL);
  float*    sel   = (float*)alloc(sizeof(float)*(size_t)Kk*256);           // 2 MB
  float*    w1e   = (float*)alloc(sizeof(float)*256*128);
  int*      inv   = (int*)  alloc(sizeof(int)*(size_t)Nn);
  int*      t32f  = (int*)  alloc(sizeof(int)*NT32);
  (void)ws_size;

  k_setupA<<<TF_B+1, 256, 0, stream>>>(x, xb, inv, w1, w1e, bases, comps, roots,
                                       WTs, t32f, bcnt, bfill, hA, hB);
  k_setupB<<<8+NCH, 256, 0, stream>>>(tidx, inv, t32f, ei, bcnt);
  k_bin<<<NCH, 256, 0, stream>>>(ei, et, bcnt, bfill, ebin);
  k_sort<<<NBK, 512, 0, stream>>>(ebin, bcnt, srcs, rowptr);

  const unsigned* hc = xb;
  unsigned* hn = hA;
  for (int l=0;l<Ll;l++){
    k_fused<<<NT32, 256, 0, stream>>>(srcs, rowptr, hc, WTs + (size_t)l*WTSL,
                                      biases + (size_t)l*Ff, (unsigned short*)hn,
                                      inv, sel, l, t32f);
    hc = hn;
    hn = (hn == hA) ? hB : hA;
  }
  k_mlp<<<Kk, 128, 0, stream>>>(sel, w1e, b1, w2, b2, out);
}

// Round 12
// 276.659 us; speedup vs baseline: 2.3291x; 1.0214x over previous
//
#include <hip/hip_runtime.h>
#include <hip/hip_bf16.h>

#define Nn 50000
#define Ee 1600000
#define Ff 64
#define Rr 5
#define Bb 4
#define Ll 4
#define Kk 2048
#define NBK 196            // dst buckets (dst>>8)
#define SEGB 1280          // segs per bucket = 5 r * 256 dst
#define MsegP (NBK*SEGB)   // 250880 padded segs; s2 = b*1280 + r*256 + dstlo
#define NT32 1563          // 32-row tiles (ceil Nn/32)
#define NCH ((Ee+8191)/8192) // 196 edge chunks
#define WTSL (12*4*64*8)   // 24576 ushorts per layer (swizzled B-frags)

typedef __attribute__((ext_vector_type(8))) short short8;
typedef __attribute__((ext_vector_type(4))) float v4f;

// ---- bf16 pack/unpack helpers (storage bf16, math fp32) ----
static __device__ __forceinline__ unsigned short f2b(float f){
  unsigned u = __float_as_uint(f);
  unsigned r = (u + 0x7fffu + ((u>>16)&1u)) >> 16;   // RTN-even
  return (unsigned short)r;
}
static __device__ __forceinline__ unsigned packbf(float lo, float hi){
  return (unsigned)f2b(lo) | ((unsigned)f2b(hi) << 16);
}
static __device__ __forceinline__ float2 unpackbf(unsigned u){
  return make_float2(__uint_as_float(u << 16), __uint_as_float(u & 0xffff0000u));
}
static __device__ __forceinline__ void acc8(float* A, uint4 g){
  float2 f;
  f=unpackbf(g.x); A[0]+=f.x; A[1]+=f.y;
  f=unpackbf(g.y); A[2]+=f.x; A[3]+=f.y;
  f=unpackbf(g.z); A[4]+=f.x; A[5]+=f.y;
  f=unpackbf(g.w); A[6]+=f.x; A[7]+=f.y;
}

// ---- fused setup A: x2b | inv_init | w1eff | W-swizzle | t32f-zero | misc-zero ----
#define XB_B 6250
#define IV_B (XB_B+196)
#define WE_B (IV_B+128)
#define WS_B (WE_B+48)
#define TF_B (WS_B+7)
__global__ __launch_bounds__(256) void k_setupA(const float* __restrict__ x, unsigned* __restrict__ xb,
    int* __restrict__ inv, const float* __restrict__ w1, float* __restrict__ w1e,
    const float* __restrict__ bases, const float* __restrict__ comps, const float* __restrict__ roots,
    unsigned short* __restrict__ WTs, int* __restrict__ t32f, int* __restrict__ bcnt,
    int* __restrict__ bfill, unsigned* __restrict__ hA, unsigned* __restrict__ hB)
{
  int b = blockIdx.x, t = threadIdx.x;
  if (b < XB_B){
    int idx = b*256 + t;                      // < Nn*32 exactly
    int n = idx >> 5, j = idx & 31;
    float2 v = *(const float2*)&x[(size_t)n*64 + 2*j];
    xb[idx] = packbf(v.x, v.y);
  } else if (b < IV_B){
    int i = (b-XB_B)*256 + t;
    if (i < Nn) inv[i] = -1;
  } else if (b < WE_B){
    int idx = (b-IV_B)*256 + t;               // < 256*128 exactly
    int i = idx >> 7, j = idx & 127;
    w1e[idx] = w1[i*128 + j] + w1[(i+256)*128 + j];
  } else if (b < WS_B){
    int gid = (b-WE_B)*256 + t;               // < 12288 exactly
    int lane = gid & 63, nb = (gid>>6)&3, idx2 = gid>>8;  // idx2 = l*12+kk
    int l = idx2/12, kk = idx2 - l*12;
    int o = nb*16 + (lane & 15);
    int kbase = kk*32 + (lane>>4)*8;
    const float* basesl = bases + (size_t)l*Bb*Ff*Ff;
    const float* compsl = comps + (size_t)l*Rr*Bb;
    const float* rootsl = roots + (size_t)l*Ff*Ff;
    unsigned short* wp = WTs + (size_t)gid*8;
    #pragma unroll
    for (int j=0;j<8;j++){
      int k = kbase + j;
      float s;
      if (k < 320){
        int c = k >> 6, i = k & 63;
        s = 0.f;
        #pragma unroll
        for (int bb2=0;bb2<Bb;bb2++)
          s += compsl[c*Bb+bb2] * basesl[(bb2*Ff + i)*Ff + o];
      } else {
        s = rootsl[(k-320)*Ff + o];
      }
      wp[j] = f2b(s);
    }
  } else if (b < TF_B){
    int i = (b-WS_B)*256 + t;
    if (i < NT32) t32f[i] = 0;
  } else {
    if (t < NBK+1) bcnt[t] = 0;
    if (t < NBK) bfill[t] = 0;
    if (t < 32){
      xb[(size_t)Nn*32 + t] = 0;              // sentinel rows (zero)
      hA[(size_t)Nn*32 + t] = 0;
      hB[(size_t)Nn*32 + t] = 0;
    }
  }
}

// ---- setup B: target-index writes (blocks 0..7) + bucket histogram (blocks 8..8+NCH)
__global__ __launch_bounds__(256) void k_setupB(const int* __restrict__ tidx, int* __restrict__ inv,
                                                int* __restrict__ t32f, const int* __restrict__ ei,
                                                int* __restrict__ bcnt){
  int b = blockIdx.x;
  if (b < 8){
    int k = b*256 + threadIdx.x;
    if (k < Kk){
      int n = tidx[k];
      inv[n] = k;
      t32f[n >> 5] = 1;   // benign race; 32-row tiles
    }
  } else {
    __shared__ int h[NBK];
    int t = threadIdx.x;
    for (int i=t;i<NBK;i+=256) h[i]=0;
    __syncthreads();
    int base = (b-8)*8192;
    for (int i=0;i<32;i++){
      int e = base + i*256 + t;
      if (e < Ee) atomicAdd(&h[ei[Ee+e]>>8], 1);
    }
    __syncthreads();
    for (int i=t;i<NBK;i+=256) if (h[i]) atomicAdd(&bcnt[i], h[i]);
  }
}

// bin edges into bucket-grouped ebin[]; packed u32 = src | dstlo8<<16 | r<<24
// bucket bases computed locally from bcnt (196-entry LDS scan); bfill = global cursors (0-based)
__global__ __launch_bounds__(256) void k_bin(const int* __restrict__ ei, const int* __restrict__ et,
                                             const int* __restrict__ bcnt, int* __restrict__ bfill,
                                             unsigned* __restrict__ ebin){
  __shared__ unsigned led[8192];
  __shared__ int h[NBK], gb[NBK];
  __shared__ int ex[256];
  int t = threadIdx.x;
  for (int i=t;i<NBK;i+=256) h[i]=0;
  int v = (t < NBK) ? bcnt[t] : 0;
  ex[t] = v;
  __syncthreads();
  int base = blockIdx.x*8192;
  for (int i=0;i<32;i++){
    int e = base + i*256 + t;
    if (e < Ee){
      int src = ei[e];
      int dst = ei[Ee+e];
      int r = et[e];
      led[i*256+t] = (unsigned)src | ((unsigned)(dst&255)<<16) | ((unsigned)r<<24);
      atomicAdd(&h[dst>>8], 1);
    }
  }
  __syncthreads();
  #pragma unroll
  for (int off=1; off<256; off<<=1){
    int x = (t>=off) ? ex[t-off] : 0;
    __syncthreads();
    ex[t] += x;
    __syncthreads();
  }
  if (t < NBK && h[t]){ gb[t] = ex[t] - v + atomicAdd(&bfill[t], h[t]); }
  if (t < NBK) h[t] = 0;
  __syncthreads();
  for (int i=0;i<32;i++){
    int e = base + i*256 + t;
    if (e < Ee){
      int b2 = ei[Ee+e]>>8;
      int off = atomicAdd(&h[b2], 1);
      ebin[gb[b2]+off] = led[i*256+t];
    }
  }
}

// per-bucket seg sort: counts -> scan -> rowptr + scatter srcs (bucket-private region)
// bucket base computed locally by reducing bcnt[0..b)
__global__ __launch_bounds__(512) void k_sort(const unsigned* __restrict__ ebin, const int* __restrict__ bcnt,
                                              unsigned short* __restrict__ srcs, int* __restrict__ rowptr){
  __shared__ int cntA[SEGB], excA[SEGB];
  __shared__ int red[512];
  int b = blockIdx.x, t = threadIdx.x;
  red[t] = (t < b) ? bcnt[t] : 0;
  __syncthreads();
  #pragma unroll
  for (int off=256; off>0; off>>=1){
    if (t < off) red[t] += red[t+off];
    __syncthreads();
  }
  int base = red[0];
  int cnt = bcnt[b];
  if (b == 0 && t == 0) rowptr[MsegP] = Ee;
  for (int i=t;i<SEGB;i+=512) cntA[i]=0;
  __syncthreads();
  for (int i=t;i<cnt;i+=512){
    unsigned u = ebin[base+i];
    int segl = (int)((u>>24)&7u)*256 + (int)((u>>16)&255u);
    atomicAdd(&cntA[segl], 1);
  }
  __syncthreads();
  for (int i=t;i<SEGB;i+=512) excA[i]=cntA[i];
  __syncthreads();
  for (int off=1; off<SEGB; off<<=1){
    int i0=t, i1=t+512, i2=t+1024;
    int v0 = (i0>=off)? excA[i0-off] : 0;
    int v1 = (i1>=off)? excA[i1-off] : 0;
    int v2 = (i2<SEGB && i2>=off)? excA[i2-off] : 0;
    __syncthreads();
    excA[i0]+=v0;
    excA[i1]+=v1;
    if (i2<SEGB) excA[i2]+=v2;
    __syncthreads();
  }
  for (int i=t;i<SEGB;i+=512){
    int ex = excA[i]-cntA[i];
    excA[i] = ex;
    rowptr[b*SEGB+i] = base + ex;
    cntA[i] = 0;
  }
  __syncthreads();
  for (int i=t;i<cnt;i+=512){
    unsigned u = ebin[base+i];
    int segl = (int)((u>>24)&7u)*256 + (int)((u>>16)&255u);
    int off = atomicAdd(&cntA[segl], 1);
    srcs[base + excA[segl] + off] = (unsigned short)(u & 0xffffu);
  }
}

#define LDROW(IDX) (*(const uint4*)&h2[(size_t)(IDX)*32 + li*4])

// ---- fused aggregation + MFMA combine (best measured config: R8, 278.4 us).
// NOTE: __launch_bounds__(256,8) -> 32-VGPR target -> scratch spill, 2.3x slower
// (R10). Packed-f32 accumulate: null (R11). Slot gating via wave-max: negative
// (R6). Keep this form.
// Phase 1: 32 groups of 8 lanes; group g owns segment (r, dst=d0+g).
//          Metadata prefetched; 12 flat sentinel-padded slots (P(deg>12)=1.7%),
//          8-deep load pipeline. Divergent tail for deg>12.
// Phase 2: 4 waves do [32,384]@[384,64] MFMA (2 row-blocks per wave).
// Layer Ll-1 is gated by t32f (tiles containing a target node) and skips hn.
__global__ __launch_bounds__(256, 4) void k_fused(const unsigned short* __restrict__ srcs,
    const int* __restrict__ rowptr, const unsigned* __restrict__ h2,
    const unsigned short* __restrict__ WTsl, const float* __restrict__ bias,
    unsigned short* __restrict__ hn, const int* __restrict__ inv, float* __restrict__ sel,
    int layer, const int* __restrict__ t32f)
{
  if (layer == Ll-1 && t32f[blockIdx.x] == 0) return;
  __shared__ __align__(16) unsigned short ytile[5*32*64];   // 20 KB, XOR-swizzled rows
  char* yb = (char*)ytile;
  int tid = threadIdx.x;
  int grp = tid >> 3;                 // 0..31: dst row within tile
  int li  = tid & 7;                  // 16 B slice of the 128 B feature row
  int grp8 = (tid & 63) & 56;         // group base lane within the wave
  int d0 = blockIdx.x * 32;
  int segbase = (d0 >> 8)*SEGB + (d0 & 255) + grp;

  // prefetch all per-r metadata: 10 independent rowptr loads, then srcs bursts
  int p[Rr], dg[Rr];
  #pragma unroll
  for (int r=0;r<Rr;r++){
    p[r]  = rowptr[segbase + r*256];
    dg[r] = rowptr[segbase + r*256 + 1] - p[r];
  }
  unsigned b0[Rr], b1r[Rr];
  #pragma unroll
  for (int r=0;r<Rr;r++){
    b0[r]  = srcs[p[r] + li];          // srcs padded by 64
    b1r[r] = srcs[p[r] + 8 + li];
  }

  #pragma unroll
  for (int r=0;r<Rr;r++){
    int deg = dg[r];
    int id[12];
    #pragma unroll
    for (int j=0;j<12;j++){
      int vsh = __shfl((int)((j<8)? b0[r] : b1r[r]), grp8 + (j&7), 64);
      id[j] = (j < deg) ? vsh : Nn;     // sentinel row = zeros (L1-hot)
    }
    float A[8] = {0.f,0.f,0.f,0.f,0.f,0.f,0.f,0.f};
    uint4 g0=LDROW(id[0]), g1=LDROW(id[1]), g2=LDROW(id[2]), g3=LDROW(id[3]),
          g4=LDROW(id[4]), g5=LDROW(id[5]), g6=LDROW(id[6]), g7=LDROW(id[7]);
    acc8(A,g0); g0=LDROW(id[ 8]);
    acc8(A,g1); g1=LDROW(id[ 9]);
    acc8(A,g2); g2=LDROW(id[10]);
    acc8(A,g3); g3=LDROW(id[11]);
    acc8(A,g4); acc8(A,g5); acc8(A,g6); acc8(A,g7);
    acc8(A,g0); acc8(A,g1); acc8(A,g2); acc8(A,g3);
    if (deg > 12){                       // rare (1.7% of segments): divergent tail
      for (int j=12;j<deg;j++){
        uint4 gt = LDROW((int)srcs[p[r]+j]);
        acc8(A, gt);
      }
    }
    float sc = (deg > 0) ? 1.0f/(float)deg : 0.f;
    uint4 o;
    o.x = packbf(A[0]*sc, A[1]*sc);
    o.y = packbf(A[2]*sc, A[3]*sc);
    o.z = packbf(A[4]*sc, A[5]*sc);
    o.w = packbf(A[6]*sc, A[7]*sc);
    int tr = r*32 + grp;
    *(uint4*)(yb + ((tr*128 + li*16) ^ ((tr&7)<<4))) = o;
  }
  __syncthreads();

  // ---- MFMA phase: wave wv owns output columns [wv*16, wv*16+16), 2 row-blocks
  int wv = tid >> 6;
  int lane = tid & 63;
  int m = lane & 15, q = lane >> 4;
  const unsigned short* wp = WTsl + (size_t)lane*8 + (size_t)wv*512;
  const char* h2c = (const char*)h2;
  int row0 = d0 + m, row1 = d0 + 16 + m;
  int row0c = (row0 < Nn) ? row0 : Nn-1;
  int row1c = (row1 < Nn) ? row1 : Nn-1;
  v4f acc0 = {0.f,0.f,0.f,0.f}, acc1 = {0.f,0.f,0.f,0.f};
  #pragma unroll
  for (int kk=0; kk<12; kk++){
    short8 a0, a1;
    if (kk < 10){
      int rb = (kk>>1)*32;
      a0 = *(const short8*)(yb + (((rb+m   )*128 + (kk&1)*64 + q*16) ^ ((m&7)<<4)));
      a1 = *(const short8*)(yb + (((rb+16+m)*128 + (kk&1)*64 + q*16) ^ ((m&7)<<4)));
    } else {
      a0 = *(const short8*)(h2c + (size_t)row0c*128 + (size_t)(kk&1)*64 + q*16);
      a1 = *(const short8*)(h2c + (size_t)row1c*128 + (size_t)(kk&1)*64 + q*16);
    }
    short8 bf = *(const short8*)(wp + (size_t)kk*2048);
    acc0 = __builtin_amdgcn_mfma_f32_16x16x32_bf16(a0, bf, acc0, 0, 0, 0);
    acc1 = __builtin_amdgcn_mfma_f32_16x16x32_bf16(a1, bf, acc1, 0, 0, 0);
  }
  float bc = bias[wv*16 + m];
  #pragma unroll
  for (int j=0;j<4;j++){
    int node0 = d0 + q*4 + j;
    int node1 = d0 + 16 + q*4 + j;
    float r0 = tanhf(acc0[j] + bc);
    float r1 = tanhf(acc1[j] + bc);
    if (node0 < Nn){
      if (layer != Ll-1) hn[(size_t)node0*64 + wv*16 + m] = f2b(r0);
      int k = inv[node0];
      if (k >= 0) sel[(size_t)k*256 + layer*64 + wv*16 + m] = r0;
    }
    if (node1 < Nn){
      if (layer != Ll-1) hn[(size_t)node1*64 + wv*16 + m] = f2b(r1);
      int k = inv[node1];
      if (k >= 0) sel[(size_t)k*256 + layer*64 + wv*16 + m] = r1;
    }
  }
}

__global__ __launch_bounds__(128) void k_mlp(const float* __restrict__ sel, const float* __restrict__ w1e,
    const float* __restrict__ b1, const float* __restrict__ w2, const float* __restrict__ b2,
    float* __restrict__ out)
{
  __shared__ float sfeat[256];
  __shared__ float partial[2];
  int k = blockIdx.x, j = threadIdx.x;
  for (int idx=j; idx<256; idx+=128) sfeat[idx] = sel[(size_t)k*256 + idx];
  __syncthreads();
  float a = b1[j];
  for (int i=0;i<256;i++) a += sfeat[i] * w1e[i*128 + j];
  a = fmaxf(a, 0.f);
  float v = a * w2[j];
  #pragma unroll
  for (int off=32; off>0; off>>=1) v += __shfl_down(v, off, 64);
  if ((j & 63) == 0) partial[j>>6] = v;
  __syncthreads();
  if (j == 0) out[k] = partial[0] + partial[1] + b2[0];
}

extern "C" void kernel_launch(void* const* d_in, const int* in_sizes, int n_in,
                              void* d_out, int out_size, void* d_ws, size_t ws_size,
                              hipStream_t stream){
  const float* x     = (const float*)d_in[0];
  const int*  ei     = (const int*)d_in[1];
  const int*  et     = (const int*)d_in[2];
  const int*  tidx   = (const int*)d_in[3];
  const float* bases = (const float*)d_in[4];
  const float* comps = (const float*)d_in[5];
  const float* roots = (const float*)d_in[6];
  const float* biases= (const float*)d_in[7];
  const float* w1    = (const float*)d_in[8];
  const float* b1    = (const float*)d_in[9];
  const float* w2    = (const float*)d_in[10];
  const float* b2    = (const float*)d_in[11];
  float* out = (float*)d_out;

  char* wsp = (char*)d_ws;
  size_t off = 0;
  auto alloc = [&](size_t bytes)->void*{ void* p = wsp + off; off += (bytes + 255) & ~size_t(255); return p; };
  unsigned* xb    = (unsigned*)alloc(sizeof(unsigned)*((size_t)Nn+1)*32);  // +sentinel row
  unsigned* hA    = (unsigned*)alloc(sizeof(unsigned)*((size_t)Nn+1)*32);
  unsigned* hB    = (unsigned*)alloc(sizeof(unsigned)*((size_t)Nn+1)*32);
  unsigned* ebin  = (unsigned*)alloc(sizeof(unsigned)*(size_t)Ee);         // 6.4 MB
  int*      bcnt  = (int*)  alloc(sizeof(int)*(NBK+1));
  int*      bfill = (int*)  alloc(sizeof(int)*(NBK));
  int*      rowptr= (int*)  alloc(sizeof(int)*(MsegP+1));                  // 1 MB
  unsigned short* srcs = (unsigned short*)alloc(sizeof(unsigned short)*((size_t)Ee+64)); // padded
  unsigned short* WTs  = (unsigned short*)alloc(sizeof(unsigned short)*(size_t)Ll*WTSL);
  float*    sel   = (float*)alloc(sizeof(float)*(size_t)Kk*256);           // 2 MB
  float*    w1e   = (float*)alloc(sizeof(float)*256*128);
  int*      inv   = (int*)  alloc(sizeof(int)*(size_t)Nn);
  int*      t32f  = (int*)  alloc(sizeof(int)*NT32);
  (void)ws_size;

  k_setupA<<<TF_B+1, 256, 0, stream>>>(x, xb, inv, w1, w1e, bases, comps, roots,
                                       WTs, t32f, bcnt, bfill, hA, hB);
  k_setupB<<<8+NCH, 256, 0, stream>>>(tidx, inv, t32f, ei, bcnt);
  k_bin<<<NCH, 256, 0, stream>>>(ei, et, bcnt, bfill, ebin);
  k_sort<<<NBK, 512, 0, stream>>>(ebin, bcnt, srcs, rowptr);

  const unsigned* hc = xb;
  unsigned* hn = hA;
  for (int l=0;l<Ll;l++){
    k_fused<<<NT32, 256, 0, stream>>>(srcs, rowptr, hc, WTs + (size_t)l*WTSL,
                                      biases + (size_t)l*Ff, (unsigned short*)hn,
                                      inv, sel, l, t32f);
    hc = hn;
    hn = (hn == hA) ? hB : hA;
  }
  k_mlp<<<Kk, 128, 0, stream>>>(sel, w1e, b1, w2, b2, out);
}